// Round 9
// baseline (11106.026 us; speedup 1.0000x reference)
//
#include <hip/hip_runtime.h>
#include <stdint.h>

// ---------------------------------------------------------------------------
// BiLSTM encoder, persistent MFMA kernel (Round 9 = R8 + ring k-offset fix).
// Transport: agent-scope relaxed atomics via IC (PROVEN in R4/R5) — no XCD /
// dispatch assumptions (G16-safe). 8 groups = blk&7 -> (dir,layer,bhalf),
// 32 blocks/group, 16 hidden units/block (64 z-cols).
// Critical chain = ONE H-wave, no barrier inside it:
//   poll hflags -> LOADA h (IC) -> 96 MFMA (col-split, full h-half K) ->
//   intra-wave LDS transpose -> pointwise -> STOREA h(u64) -> vmcnt(0) ->
//   STOREA per-wave hflag.
// X-waves (k-split, 96 MFMA) compute zx(s+1) one epoch ahead + drain
// deferred ring/out stores; single end-of-epoch __syncthreads; L0 X-wave0
// publishes xflag after ring-store drain (L1's ring dependency).
// R9 fix: computeX1's ring A-load now includes the wave's k-quarter offset
// (+wvid*128 u32 = 256 units) — R8 had X-wave1 reading y0[0..255] against
// W[256..511] (half of L1's input GEMM wrong -> absmax 0.55).
// ---------------------------------------------------------------------------

#define T_ 1024

typedef __attribute__((ext_vector_type(8))) short bf16x8;
typedef __attribute__((ext_vector_type(4))) float f32x4;
typedef __attribute__((ext_vector_type(4))) unsigned int u32x4;
typedef unsigned long long ull;

// ---- ws layout (bytes) ----
#define HFLAG_OFF 0                      // [8 grp][64 u32] (rank*2+hw)
#define XFLAG_OFF 2048                   // [8 grp][32 u32] (pad to 256B)
#define H_OFF     4096                   // [8 grp][2 par][16 b][512 u] u32
#define RING_OFF  (4096 + 8*2*32768)     // 528384: [4 reg][8 slot][16 b][256] u32
#define WS_BYTES  (RING_OFF + 4*8*16384) // 1,052,672 (== R5 proven size)
#define WS_ZERO   RING_OFF               // ring is fully written before read

// ---- lds layout (bytes) ----
#define BLO_OFF   0                      // [64 col][1024 k] u16 pitch 2048, swz
#define TEMP_OFF  131072                 // init temp [64 cc][128 kl] u16 (16KB)
#define ZX_OFF    131072                 // [2 par][2 xw][16][68] f32 (4352B each)
#define ZF_OFF    (ZX_OFF + 4*4352)      // [2 hw][16][36] f32 (2304B each)
#define SRING_OFF (ZF_OFF + 2*2304)      // [2 par][128 u32]
#define SOUT_OFF  (SRING_OFF + 2*512)    // [2 par][256 f32]
#define LDS_BYTES (SOUT_OFF + 2*1024)    // 156,160

#define LOADA(p)     __hip_atomic_load((p), __ATOMIC_RELAXED, __HIP_MEMORY_SCOPE_AGENT)
#define STOREA(p,v)  __hip_atomic_store((p), (v), __ATOMIC_RELAXED, __HIP_MEMORY_SCOPE_AGENT)

__device__ __forceinline__ float sigm(float x) { return 1.f / (1.f + __expf(-x)); }
__device__ __forceinline__ unsigned short bf16_rtn(float f) {
  unsigned u = __builtin_bit_cast(unsigned, f);
  unsigned r = u + 0x7FFFu + ((u >> 16) & 1u);
  return (unsigned short)(r >> 16);
}
__device__ __forceinline__ float bf16f(unsigned short h) {
  return __builtin_bit_cast(float, (unsigned)h << 16);
}
__device__ __forceinline__ void split_f32(float f, unsigned short& hi, unsigned short& lo) {
  hi = bf16_rtn(f); lo = bf16_rtn(f - bf16f(hi));
}
__device__ __forceinline__ unsigned packhi2(float fa, float fb) {
  return __builtin_amdgcn_perm(__builtin_bit_cast(unsigned, fb),
                               __builtin_bit_cast(unsigned, fa), 0x07060302u);
}
__device__ __forceinline__ float hipart(float f) {
  return __builtin_bit_cast(float, __builtin_bit_cast(unsigned, f) & 0xFFFF0000u);
}
__device__ __forceinline__ unsigned hiPair(unsigned w0, unsigned w1) {
  return __builtin_amdgcn_perm(w1, w0, 0x07060302u);
}
__device__ __forceinline__ unsigned loPair(unsigned w0, unsigned w1) {
  return __builtin_amdgcn_perm(w1, w0, 0x05040100u);
}

#define MFMA(ACC, Af, Bf) ACC = __builtin_amdgcn_mfma_f32_16x16x32_bf16((Af), (Bf), (ACC), 0, 0, 0)

// watchdog-capped agent polls (~1ms cap: legit jitter is us-scale; a firing
// watchdog means protocol bug -> fail fast with counters instead of hanging)
__device__ __forceinline__ void poll64(const unsigned* p, unsigned tgt, int lane) {
  for (int it = 0; it < 4000; ++it) {
    unsigned v = LOADA(p + lane);
    if (__all(v >= tgt)) return;
    __builtin_amdgcn_s_sleep(2);
  }
}
__device__ __forceinline__ void poll32(const unsigned* p, unsigned tgt, int lane) {
  for (int it = 0; it < 4000; ++it) {
    unsigned v = LOADA(p + (lane & 31));
    if (__all(v >= tgt)) return;
    __builtin_amdgcn_s_sleep(2);
  }
}

__global__ __launch_bounds__(256, 1)
void bilstm_v9(const float* __restrict__ inp, const int* __restrict__ lens,
               const float* __restrict__ Wf, const float* __restrict__ bfp,
               const float* __restrict__ Wb, const float* __restrict__ bbp,
               float* __restrict__ out, char* __restrict__ wsb) {
  extern __shared__ char lds[];
  const int tid = threadIdx.x, blk = blockIdx.x;
  const int g = blk & 7, rank = blk >> 3;           // placement-independent
  const int dir = g >> 2, layer = (g >> 1) & 1, bhalf = g & 1;
  const int j0 = rank * 16;

  unsigned* hfl_own = (unsigned*)(wsb + HFLAG_OFF) + g * 64;
  unsigned* xfl_own = (unsigned*)(wsb + XFLAG_OFF) + g * 64;
  const unsigned* hfl_l1 = (const unsigned*)(wsb + HFLAG_OFF) + (g | 2) * 64;
  const unsigned* xfl_l0 = (const unsigned*)(wsb + XFLAG_OFF) + (g & ~2) * 64;
  unsigned* hbuf = (unsigned*)(wsb + H_OFF) + (size_t)g * 2 * 8192;
  unsigned* ringbase = (unsigned*)(wsb + RING_OFF) + (size_t)(dir * 2 + bhalf) * 8 * 4096;

  const float* Wg = (dir == 0 ? Wf : Wb) + (size_t)layer * 1024 * 2048;
  const float* bg = (dir == 0 ? bfp : bbp) + layer * 2048;

  const int lane = tid & 63, wvid = tid >> 6;
  const bool isX = (wvid < 2);
  const int hw = wvid - 2;                          // 0,1 for H-waves
  const int fr = lane & 15, fq = lane >> 4;
  const int xsw = (fr & 7) << 4;

  // ---- init: W -> bf16 hi (temp->VGPR frags) / lo (LDS), chunked 128-k ----
  bf16x8 bhf[32];   // X: [nt(4)*8+kk(8)] over its k-quarter; H: [nt(2)*16+kk(16)]
#pragma unroll 1
  for (int c8 = 0; c8 < 8; ++c8) {
#pragma unroll
    for (int i = 0; i < 2; ++i) {
      int task = tid * 2 + i;                       // 512 = 128 kl x 4 gates
      int kl = task >> 2, gate = task & 3;
      int kg = c8 * 128 + kl;
      const float* src = Wg + (size_t)kg * 2048 + gate * 512 + j0;
      float4 w0 = *(const float4*)src, w1 = *(const float4*)(src + 4);
      float4 w2 = *(const float4*)(src + 8), w3 = *(const float4*)(src + 12);
      float wv[16] = {w0.x, w0.y, w0.z, w0.w, w1.x, w1.y, w1.z, w1.w,
                      w2.x, w2.y, w2.z, w2.w, w3.x, w3.y, w3.z, w3.w};
#pragma unroll
      for (int u = 0; u < 16; ++u) {
        int cc = u * 4 + gate;
        unsigned short hi, lo; split_f32(wv[u], hi, lo);
        *(unsigned short*)(lds + TEMP_OFF + cc * 256 + kl * 2) = hi;
        *(unsigned short*)(lds + BLO_OFF + cc * 2048 + ((kg * 2) ^ ((cc & 7) << 4))) = lo;
      }
    }
    __syncthreads();
    if (isX && (c8 >> 1) == wvid) {
#pragma unroll
      for (int kj = 0; kj < 4; ++kj) {
        const int kk = (c8 & 1) * 4 + kj;
        const int kl2 = (kk * 32 + fq * 8) * 2 - (c8 & 1) * 256;
#pragma unroll
        for (int nt = 0; nt < 4; ++nt)
          bhf[nt * 8 + kk] = *(const bf16x8*)(lds + TEMP_OFF + (nt * 16 + fr) * 256 + kl2);
      }
    } else if (!isX && c8 >= 4) {
#pragma unroll
      for (int kj = 0; kj < 4; ++kj) {
        const int kk = (c8 - 4) * 4 + kj;
        const int kl2 = (kj * 32 + fq * 8) * 2;
#pragma unroll
        for (int nt = 0; nt < 2; ++nt)
          bhf[nt * 16 + kk] = *(const bf16x8*)(lds + TEMP_OFF + (hw * 32 + nt * 16 + fr) * 256 + kl2);
      }
    }
    __syncthreads();
  }

  // ---- per-thread constants ----
  const int lenrow = lens[bhalf * 16 + fr];                 // X GEMM A-row
  const int lenx   = lens[bhalf * 16 + ((wvid * 64 + lane) >> 3)];  // out store
  const int pb = lane & 15, pup = lane >> 4;                // H pointwise
  const int uloc = (isX ? 0 : hw * 8) + 2 * pup;            // even unit base
  const int mylen = lens[bhalf * 16 + pb];
  float bias_[2][4];
#pragma unroll
  for (int i = 0; i < 2; ++i)
#pragma unroll
    for (int g4 = 0; g4 < 4; ++g4)
      bias_[i][g4] = bg[g4 * 512 + j0 + uloc + i];
  float c_reg[2] = {0.f, 0.f}, h_reg[2] = {0.f, 0.f};
  const int first_act = layer ? 4 : 0;

  // ---- lambdas ----
  auto computeX0 = [&](int t, int par) {            // layer0: x from HBM
    f32x4 a[4][3] = {};
    int tr = t;
    if (dir == 1) tr = (t < lenrow) ? (lenrow - 1 - t) : t;
    const float* xp = inp + ((size_t)(bhalf * 16 + fr) * T_ + tr) * 512 + wvid * 256 + fq * 8;
#pragma unroll
    for (int kk = 0; kk < 8; ++kk) {
      float4 xa = *(const float4*)(xp + kk * 32);
      float4 xb = *(const float4*)(xp + kk * 32 + 4);
      unsigned h0 = packhi2(xa.x, xa.y), h1 = packhi2(xa.z, xa.w);
      unsigned h2 = packhi2(xb.x, xb.y), h3 = packhi2(xb.z, xb.w);
      unsigned l0 = packhi2(xa.x - hipart(xa.x), xa.y - hipart(xa.y));
      unsigned l1 = packhi2(xa.z - hipart(xa.z), xa.w - hipart(xa.w));
      unsigned l2 = packhi2(xb.x - hipart(xb.x), xb.y - hipart(xb.y));
      unsigned l3 = packhi2(xb.z - hipart(xb.z), xb.w - hipart(xb.w));
      u32x4 hv = {h0, h1, h2, h3}, lv = {l0, l1, l2, l3};
      bf16x8 ah = __builtin_bit_cast(bf16x8, hv);
      bf16x8 al = __builtin_bit_cast(bf16x8, lv);
      const int ko = (wvid * 512 + kk * 64 + fq * 16) ^ xsw;
#pragma unroll
      for (int nt = 0; nt < 4; ++nt) {
        bf16x8 bl = *(const bf16x8*)(lds + BLO_OFF + (nt * 16 + fr) * 2048 + ko);
        MFMA(a[nt][0], ah, bhf[nt * 8 + kk]);
        MFMA(a[nt][1], ah, bl);
        MFMA(a[nt][2], al, bhf[nt * 8 + kk]);
      }
    }
    float* zx = (float*)(lds + ZX_OFF) + (par * 2 + wvid) * 1088;
#pragma unroll
    for (int nt = 0; nt < 4; ++nt)
#pragma unroll
      for (int r = 0; r < 4; ++r)
        zx[(fq * 4 + r) * 68 + nt * 16 + fr] = a[nt][0][r] + a[nt][1][r] + a[nt][2][r];
  };

  auto computeX1 = [&](int t, int par) {            // layer1: x = ring y0 (IC)
    poll32(xfl_l0, (unsigned)(t + 1), lane);        // ring(t) stored @ L0 epoch t+1
    f32x4 a[4][2] = {};
    // R9 FIX: + wvid*128 (u32) = this wave's 256-unit k-quarter of y0
    const ull* q = (const ull*)(ringbase + (t & 7) * 4096 + fr * 256 + wvid * 128 + fq * 4);
    ull rv[8][2];
#pragma unroll
    for (int kk = 0; kk < 8; ++kk) {
      rv[kk][0] = LOADA(q + kk * 8);
      rv[kk][1] = LOADA(q + kk * 8 + 1);
    }
#pragma unroll
    for (int kk = 0; kk < 8; ++kk) {
      bf16x8 ah = __builtin_bit_cast(bf16x8, rv[kk]);
      const int ko = (wvid * 512 + kk * 64 + fq * 16) ^ xsw;
#pragma unroll
      for (int nt = 0; nt < 4; ++nt) {
        bf16x8 bl = *(const bf16x8*)(lds + BLO_OFF + (nt * 16 + fr) * 2048 + ko);
        MFMA(a[nt][0], ah, bhf[nt * 8 + kk]);
        MFMA(a[nt][1], ah, bl);
      }
    }
    float* zx = (float*)(lds + ZX_OFF) + (par * 2 + wvid) * 1088;
#pragma unroll
    for (int nt = 0; nt < 4; ++nt)
#pragma unroll
      for (int r = 0; r < 4; ++r)
        zx[(fq * 4 + r) * 68 + nt * 16 + fr] = a[nt][0][r] + a[nt][1][r];
  };

  auto computeH = [&](int s) {   // the critical chain: poll->load->GEMM->pointwise->publish
    if (s > first_act) poll64(hfl_own, (unsigned)s, lane);
    const ull* q = (const ull*)(hbuf + (size_t)(s & 1) * 8192) + fr * 256 + fq * 4;
    f32x4 a[2][3] = {};
    ull hr[4][4];
#pragma unroll
    for (int p = 0; p < 4; ++p)
#pragma unroll
      for (int w = 0; w < 4; ++w) hr[p][w] = LOADA(q + p * 16 + w);
#pragma unroll
    for (int kk = 0; kk < 16; ++kk) {
      unsigned w0 = (unsigned)hr[kk & 3][0], w1 = (unsigned)(hr[kk & 3][0] >> 32);
      unsigned w2 = (unsigned)hr[kk & 3][1], w3 = (unsigned)(hr[kk & 3][1] >> 32);
      unsigned w4 = (unsigned)hr[kk & 3][2], w5 = (unsigned)(hr[kk & 3][2] >> 32);
      unsigned w6 = (unsigned)hr[kk & 3][3], w7 = (unsigned)(hr[kk & 3][3] >> 32);
      if (kk + 4 < 16) {
#pragma unroll
        for (int w = 0; w < 4; ++w) hr[kk & 3][w] = LOADA(q + (kk + 4) * 16 + w);
      }
      u32x4 hv = {hiPair(w0, w1), hiPair(w2, w3), hiPair(w4, w5), hiPair(w6, w7)};
      u32x4 lv = {loPair(w0, w1), loPair(w2, w3), loPair(w4, w5), loPair(w6, w7)};
      bf16x8 ah = __builtin_bit_cast(bf16x8, hv);
      bf16x8 al = __builtin_bit_cast(bf16x8, lv);
      const int ko = (1024 + kk * 64 + fq * 16) ^ xsw;
#pragma unroll
      for (int nt = 0; nt < 2; ++nt) {
        bf16x8 bl = *(const bf16x8*)(lds + BLO_OFF + (hw * 32 + nt * 16 + fr) * 2048 + ko);
        MFMA(a[nt][0], ah, bhf[nt * 16 + kk]);
        MFMA(a[nt][1], ah, bl);
        MFMA(a[nt][2], al, bhf[nt * 16 + kk]);
      }
    }
    // z = zh + zx0 + zx1 -> intra-wave LDS transpose (no barrier: all 32 cols ours)
    const float* zx0 = (const float*)(lds + ZX_OFF) + ((s & 1) * 2 + 0) * 1088;
    const float* zx1 = (const float*)(lds + ZX_OFF) + ((s & 1) * 2 + 1) * 1088;
    float* zf = (float*)(lds + ZF_OFF) + hw * 576;   // [16][36]
#pragma unroll
    for (int nt = 0; nt < 2; ++nt) {
      f32x4 v = a[nt][0] + a[nt][1] + a[nt][2];
#pragma unroll
      for (int r = 0; r < 4; ++r) {
        const int row = fq * 4 + r, col = nt * 16 + fr;
        zf[row * 36 + col] = v[r] + zx0[row * 68 + hw * 32 + col] + zx1[row * 68 + hw * 32 + col];
      }
    }
    // pointwise: lane -> (batch pb, units uloc, uloc+1)
    float4 z0 = *(const float4*)(zf + pb * 36 + 2 * pup * 4);
    float4 z1 = *(const float4*)(zf + pb * 36 + 2 * pup * 4 + 4);
    const int t = layer ? (s - 4) : s;
    const bool m = (t < mylen);
    float y[2];
    unsigned hword[2];
#pragma unroll
    for (int i = 0; i < 2; ++i) {
      float4 z = i ? z1 : z0;
      float zi = z.x + bias_[i][0], zj = z.y + bias_[i][1];
      float zfg = z.z + bias_[i][2], zo = z.w + bias_[i][3];
      float ig = sigm(zi), fg = sigm(zfg + 1.0f), og = sigm(zo);
      float cn = fg * c_reg[i] + ig * tanhf(zj);
      float hn = og * tanhf(cn);
      if (m) { c_reg[i] = cn; h_reg[i] = hn; }
      unsigned short nh, nl; split_f32(h_reg[i], nh, nl);
      hword[i] = ((unsigned)nh << 16) | nl;
      y[i] = m ? hn : 0.f;
    }
    ull hq = (ull)hword[0] | ((ull)hword[1] << 32);
    STOREA((ull*)(hbuf + (size_t)((s + 1) & 1) * 8192 + pb * 512 + j0 + uloc), hq);
    if (layer == 0) {
      unsigned rw = (unsigned)bf16_rtn(y[0]) | ((unsigned)bf16_rtn(y[1]) << 16);
      *(unsigned*)(lds + SRING_OFF + (s & 1) * 512 + (pb * 8 + hw * 4 + pup) * 4) = rw;
    } else {
      *(float2*)(lds + SOUT_OFF + (s & 1) * 1024 + (pb * 8 + hw * 4 + pup) * 8) = make_float2(y[0], y[1]);
    }
    asm volatile("s_waitcnt vmcnt(0)" ::: "memory");  // h stores visible
    STOREA(hfl_own + rank * 2 + hw, (unsigned)(s + 1));
  };

  // ---- prologue ----
  if (layer == 0 && isX) computeX0(0, 0);
  __syncthreads();

  // ---- epoch loop ----
#pragma unroll 1
  for (int s = 0; s <= 1028; ++s) {
    if (isX) {
      if (layer == 0) {
        if (wvid == 0) {
          const int tp = s - 1;
          if (tp >= 0 && tp < 1024) {
            if (s >= 9) poll64(hfl_l1, (unsigned)(s - 4), lane);  // slot reuse guard
            ull w = *(const ull*)(lds + SRING_OFF + (tp & 1) * 512 + lane * 8);
            unsigned* dst = ringbase + (tp & 7) * 4096 + (lane >> 2) * 256 + rank * 8 + 2 * (lane & 3);
            STOREA((ull*)dst, w);
          }
          asm volatile("s_waitcnt vmcnt(0)" ::: "memory");
          STOREA(xfl_own + rank, (unsigned)s);
        }
        if (s <= 1022) computeX0(s + 1, (s + 1) & 1);
      } else {
        const int tp = s - 5;                         // deferred out store
        if (tp >= 0 && tp < 1024) {
          const int i = wvid * 64 + lane, b = i >> 3, p = i & 7;
          float2 yv = *(const float2*)(lds + SOUT_OFF + ((s - 1) & 1) * 1024 + (b * 8 + p) * 8);
          const int bg2 = bhalf * 16 + b;
          const int ot = (dir == 1 && tp < lenx) ? (lenx - 1 - tp) : tp;
          *(float2*)(out + ((size_t)bg2 * T_ + ot) * 1024 + dir * 512 + j0 + 2 * p) = yv;
        }
        if (s >= 3 && s <= 1026) computeX1(s - 3, (s + 1) & 1);
      }
    } else {
      const bool pa = layer ? (s >= 4 && s <= 1027) : (s <= 1023);
      if (pa) computeH(s);
    }
    __syncthreads();   // orders zx(s+1), SRING/SOUT staging for next epoch
  }
}

extern "C" void kernel_launch(void* const* d_in, const int* in_sizes, int n_in,
                              void* d_out, int out_size, void* d_ws, size_t ws_size,
                              hipStream_t stream) {
  const float* inp   = (const float*)d_in[0];
  const int*   lensp = (const int*)d_in[1];
  const float* Wf    = (const float*)d_in[2];
  const float* bfp   = (const float*)d_in[3];
  const float* Wb    = (const float*)d_in[4];
  const float* bbp   = (const float*)d_in[5];
  float*       outp  = (float*)d_out;
  char*        wsp   = (char*)d_ws;
  (void)in_sizes; (void)n_in; (void)out_size; (void)ws_size;

  hipMemsetAsync(d_ws, 0, WS_ZERO, stream);   // flags + h (ring written-before-read)
  hipFuncSetAttribute((const void*)bilstm_v9,
                      hipFuncAttributeMaxDynamicSharedMemorySize, LDS_BYTES);
  bilstm_v9<<<dim3(256), dim3(256), LDS_BYTES, stream>>>(
      inp, lensp, Wf, bfp, Wb, bbp, outp, wsp);
}